// Round 1
// baseline (493.316 us; speedup 1.0000x reference)
//
#include <hip/hip_runtime.h>
#include <cstdint>
#include <cstddef>

typedef _Float16 half8 __attribute__((ext_vector_type(8)));
typedef __fp16 fp16x2 __attribute__((ext_vector_type(2)));
typedef float floatx16 __attribute__((ext_vector_type(16)));
typedef unsigned uint2v __attribute__((ext_vector_type(2)));

// ws: frag-linear weight blobs. chunk = 1024 B = 64 lanes x 8 f16, lane l holds
// A[row = tile*32 + (l&31)][k = kchunk*16 + (l>>5)*8 + i], i=0..7.
//   W0c [C][16 chunks]  @ f16 0       (mt 0..3) x (ks 0..3); k<48: W0[(16+k)*128+j],
//                                     k==48: cbias(c,j)=b0[j]+emb_c.W0[0:16,j], else 0
//   W1  [36 chunks]     @ C*8192      (mt 0..3) x (ks 0..8); k<128: W1[k*128+j], k==128: b1[j], else 0
//   W2  [9 chunks]      @ C*8192+18432  (ks 0..8); o=(l&31): o<3 ? (k<128? W2[k*3+o] : k==128? b2[o] : 0) : 0

__global__ void vdc_prep_kernel(const float* __restrict__ W0,
                                const float* __restrict__ W1,
                                const float* __restrict__ W2,
                                const float* __restrict__ b0,
                                const float* __restrict__ b1,
                                const float* __restrict__ b2,
                                const float* __restrict__ emb_tab,
                                const int* __restrict__ embed_ids,
                                int C,
                                _Float16* __restrict__ ws) {
    int i = blockIdx.x * 256 + threadIdx.x;
    int w0end = C * 8192;
    int w1end = w0end + 18432;
    int w2end = w1end + 4608;
    float v = 0.0f;
    if (i < w0end) {
        int c = i >> 13, r = i & 8191;
        int ci = r >> 9, l = (r >> 3) & 63, ii = r & 7;
        int mt = ci >> 2, ks = ci & 3;
        int j  = mt * 32 + (l & 31);
        int kk = ks * 16 + (l >> 5) * 8 + ii;
        if (kk < 48) v = W0[(16 + kk) * 128 + j];
        else if (kk == 48) {
            int id = embed_ids[c];
            v = b0[j];
            #pragma unroll
            for (int e = 0; e < 16; ++e)
                v += emb_tab[(size_t)id * 16 + e] * W0[e * 128 + j];
        }
        ws[i] = (_Float16)v;
    } else if (i < w1end) {
        int r = i - w0end;
        int ci = r >> 9, l = (r >> 3) & 63, ii = r & 7;
        int mt = ci / 9, ks = ci - mt * 9;
        int j  = mt * 32 + (l & 31);
        int kk = ks * 16 + (l >> 5) * 8 + ii;
        if (kk < 128) v = W1[kk * 128 + j];
        else if (kk == 128) v = b1[j];
        ws[i] = (_Float16)v;
    } else if (i < w2end) {
        int r = i - w1end;
        int ks = r >> 9, l = (r >> 3) & 63, ii = r & 7;
        int o  = l & 31;
        int kk = ks * 16 + (l >> 5) * 8 + ii;
        if (o < 3) {
            if (kk < 128) v = W2[kk * 3 + o];
            else if (kk == 128) v = b2[o];
        }
        ws[i] = (_Float16)v;
    }
}

union U4 { unsigned u[4]; half8 h; };

__device__ __forceinline__ unsigned pkr(float a, float b) {
    union { fp16x2 h; unsigned u; } x;
    x.h = __builtin_amdgcn_cvt_pkrtz(a, b);
    return x.u;
}

// pack with round-toward-zero, then clamp both f16 halves to >= 0 (one v_pk_max_f16)
__device__ __forceinline__ unsigned pkrelu(float a, float b) {
    union { fp16x2 h; unsigned u; } x;
    x.h = __builtin_amdgcn_cvt_pkrtz(a, b);
    fp16x2 z = {(__fp16)0.0f, (__fp16)0.0f};
    x.h = __builtin_elementwise_max(x.h, z);
    return x.u;
}

// acc tile (C-layout) -> two B-frag half8 chunks (relu + pack + half-wave exchange).
__device__ __forceinline__ void transition(const floatx16& a, int hl,
                                           half8& lo, half8& hi) {
    unsigned p0 = pkrelu(a[0],  a[1]);
    unsigned p1 = pkrelu(a[2],  a[3]);
    unsigned p2 = pkrelu(a[4],  a[5]);
    unsigned p3 = pkrelu(a[6],  a[7]);
    unsigned p4 = pkrelu(a[8],  a[9]);
    unsigned p5 = pkrelu(a[10], a[11]);
    unsigned p6 = pkrelu(a[12], a[13]);
    unsigned p7 = pkrelu(a[14], a[15]);
    U4 L, H;
#if __has_builtin(__builtin_amdgcn_permlane32_swap)
    uint2v s02 = __builtin_amdgcn_permlane32_swap(p0, p2, false, false);
    uint2v s13 = __builtin_amdgcn_permlane32_swap(p1, p3, false, false);
    uint2v s46 = __builtin_amdgcn_permlane32_swap(p4, p6, false, false);
    uint2v s57 = __builtin_amdgcn_permlane32_swap(p5, p7, false, false);
    L.u[0] = s02[0]; L.u[1] = s13[0]; L.u[2] = s02[1]; L.u[3] = s13[1];
    H.u[0] = s46[0]; H.u[1] = s57[0]; H.u[2] = s46[1]; H.u[3] = s57[1];
    (void)hl;
#else
    unsigned r0 = __shfl_xor(hl ? p0 : p2, 32);
    unsigned r1 = __shfl_xor(hl ? p1 : p3, 32);
    unsigned r2 = __shfl_xor(hl ? p4 : p6, 32);
    unsigned r3 = __shfl_xor(hl ? p5 : p7, 32);
    L.u[0] = hl ? r0 : p0;
    L.u[1] = hl ? r1 : p1;
    L.u[2] = hl ? p2 : r0;
    L.u[3] = hl ? p3 : r1;
    H.u[0] = hl ? r2 : p4;
    H.u[1] = hl ? r3 : p5;
    H.u[2] = hl ? p6 : r2;
    H.u[3] = hl ? p7 : r3;
#endif
    lo = L.h; hi = H.h;
}

// SH frag (chunk 2) for one element given unit-unnormalized dir
__device__ __forceinline__ void sh_frag(float dx, float dy, float dz,
                                        int hl, int nbu, half8& o2) {
    float nrm = sqrtf(dx * dx + dy * dy + dz * dz);
    float inv = 1.0f / fmaxf(nrm, 1e-12f);
    float x = dx * inv, y = dy * inv, z = dz * inv;

    float z2     = z * z;
    float fTmp0B = -1.092548430592079f * z;
    float fC1    = x * x - y * y;
    float fS1    = 2.0f * x * y;
    float fTmp0C = -2.285228997322329f * z2 + 0.4570457994644658f;
    float fTmp1B = 1.445305721320277f * z;
    float fC2    = x * fC1 - y * fS1;
    float fS2    = x * fS1 + y * fC1;

    float sh[16];
    sh[0]  = 0.2820947917738781f;
    sh[1]  = -0.48860251190292f * y;
    sh[2]  = 0.48860251190292f * z;
    sh[3]  = -0.48860251190292f * x;
    sh[4]  = 0.5462742152960395f * fS1;
    sh[5]  = fTmp0B * y;
    sh[6]  = 0.9461746957575601f * z2 - 0.3153915652525201f;
    sh[7]  = fTmp0B * x;
    sh[8]  = 0.5462742152960395f * fC1;
    sh[9]  = -0.5900435899266435f * fS2;
    sh[10] = fTmp1B * fS1;
    sh[11] = fTmp0C * y;
    sh[12] = z * (1.865881662950577f * z2 - 1.119528997770346f);
    sh[13] = fTmp0C * x;
    sh[14] = fTmp1B * fC1;
    sh[15] = -0.5900435899266435f * fC2;
    #pragma unroll
    for (int i = 0; i < 16; ++i) if (i >= nbu) sh[i] = 0.0f;

    float s0 = hl ? sh[8]  : sh[0];
    float s1 = hl ? sh[9]  : sh[1];
    float s2 = hl ? sh[10] : sh[2];
    float s3 = hl ? sh[11] : sh[3];
    float s4 = hl ? sh[12] : sh[4];
    float s5 = hl ? sh[13] : sh[5];
    float s6 = hl ? sh[14] : sh[6];
    float s7 = hl ? sh[15] : sh[7];
    U4 u2;
    u2.u[0] = pkr(s0, s1); u2.u[1] = pkr(s2, s3);
    u2.u[2] = pkr(s4, s5); u2.u[3] = pkr(s6, s7);
    o2 = u2.h;
}

// build layer0 B-frags for BOTH element tiles; all global loads issued before
// any math so the HBM latency is exposed once, not ~10 times.
__device__ __forceinline__ void build_bfrags2(
    const float* __restrict__ feats, const float* __restrict__ dirs,
    size_t cN, int na, int nb, int hl, int nbu,
    half8& ao0, half8& ao1, half8& ao2,
    half8& bo0, half8& bo1, half8& bo2)
{
    const float* fa = feats + (size_t)na * 32 + hl * 8;
    const float* fb = feats + (size_t)nb * 32 + hl * 8;
    float4 fa0 = *(const float4*)(fa);
    float4 fa1 = *(const float4*)(fa + 4);
    float4 fa2 = *(const float4*)(fa + 16);
    float4 fa3 = *(const float4*)(fa + 20);
    float4 fb0 = *(const float4*)(fb);
    float4 fb1 = *(const float4*)(fb + 4);
    float4 fb2 = *(const float4*)(fb + 16);
    float4 fb3 = *(const float4*)(fb + 20);
    const float* dpa = dirs + (cN + na) * 3;
    const float* dpb = dirs + (cN + nb) * 3;
    float dax = dpa[0], day = dpa[1], daz = dpa[2];
    float dbx = dpb[0], dby = dpb[1], dbz = dpb[2];

    U4 u;
    u.u[0] = pkr(fa0.x, fa0.y); u.u[1] = pkr(fa0.z, fa0.w);
    u.u[2] = pkr(fa1.x, fa1.y); u.u[3] = pkr(fa1.z, fa1.w);
    ao0 = u.h;
    u.u[0] = pkr(fa2.x, fa2.y); u.u[1] = pkr(fa2.z, fa2.w);
    u.u[2] = pkr(fa3.x, fa3.y); u.u[3] = pkr(fa3.z, fa3.w);
    ao1 = u.h;
    u.u[0] = pkr(fb0.x, fb0.y); u.u[1] = pkr(fb0.z, fb0.w);
    u.u[2] = pkr(fb1.x, fb1.y); u.u[3] = pkr(fb1.z, fb1.w);
    bo0 = u.h;
    u.u[0] = pkr(fb2.x, fb2.y); u.u[1] = pkr(fb2.z, fb2.w);
    u.u[2] = pkr(fb3.x, fb3.y); u.u[3] = pkr(fb3.z, fb3.w);
    bo1 = u.h;

    sh_frag(dax, day, daz, hl, nbu, ao2);
    sh_frag(dbx, dby, dbz, hl, nbu, bo2);
}

#define MFMA(a, b, c) __builtin_amdgcn_mfma_f32_32x32x16_f16((a), (b), (c), 0, 0, 0)
#define LDF(off) (*(const half8*)(fr + (off)))
#define GW2(ch) (*(const half8*)(w2p + (ch) * 512 + lane * 8))

// layer 0, tile MT: chains start from the shared opaque-zero C (D != C MFMA),
// killing the per-chain 16x v_accvgpr_write zero-init.
#define L0_MT(MT, HA0, HA1, HB0, HB1)                                    \
    do {                                                                 \
        half8 t0 = LDF(((MT) * 4 + 0) * 1024);                           \
        half8 t1 = LDF(((MT) * 4 + 1) * 1024);                           \
        half8 t2 = LDF(((MT) * 4 + 2) * 1024);                           \
        half8 t3 = LDF(((MT) * 4 + 3) * 1024);                           \
        floatx16 ca = MFMA(t0, ax0, z);                                  \
        floatx16 cb = MFMA(t0, bx0, z);                                  \
        ca = MFMA(t1, ax1, ca); cb = MFMA(t1, bx1, cb);                  \
        ca = MFMA(t2, ax2, ca); cb = MFMA(t2, bx2, cb);                  \
        ca = MFMA(t3, bbias, ca); cb = MFMA(t3, bbias, cb);              \
        transition(ca, hl, HA0, HA1);                                    \
        transition(cb, hl, HB0, HB1);                                    \
    } while (0)

#define L1_KS(MT, KS, HA, HB)                                            \
    do {                                                                 \
        half8 q = LDF(16384 + ((MT) * 9 + (KS)) * 1024);                 \
        ca = MFMA(q, HA, ca); cb = MFMA(q, HB, cb);                      \
    } while (0)

#define PFW2(M) w2a##M = GW2(2 * (M)); w2b##M = GW2(2 * (M) + 1)

// layer 1 with fused layer-2: W2 pair for THIS tile prefetched one MT earlier;
// L2 accumulates into 3 scalar f32 per chain (no persistent acc3 AGPR tile).
#define L1_MT(MT, W2A, W2B, PF)                                          \
    do {                                                                 \
        floatx16 ca, cb;                                                 \
        { half8 q = LDF(16384 + ((MT) * 9 + 0) * 1024);                  \
          ca = MFMA(q, ha0, z); cb = MFMA(q, hb0, z); }                  \
        PF;                                                              \
        L1_KS(MT, 1, ha1, hb1);                                          \
        L1_KS(MT, 2, ha2, hb2);                                          \
        L1_KS(MT, 3, ha3, hb3);                                          \
        L1_KS(MT, 4, ha4, hb4);                                          \
        L1_KS(MT, 5, ha5, hb5);                                          \
        L1_KS(MT, 6, ha6, hb6);                                          \
        L1_KS(MT, 7, ha7, hb7);                                          \
        L1_KS(MT, 8, bbias, bbias);                                      \
        half8 g0, g1;                                                    \
        transition(ca, hl, g0, g1);                                      \
        { floatx16 ct = MFMA(W2A, g0, z); ct = MFMA(W2B, g1, ct);        \
          oa0 += ct[0]; oa1 += ct[1]; oa2 += ct[2]; }                    \
        transition(cb, hl, g0, g1);                                      \
        { floatx16 ct = MFMA(W2A, g0, z); ct = MFMA(W2B, g1, ct);        \
          ob0 += ct[0]; ob1 += ct[1]; ob2 += ct[2]; }                    \
    } while (0)

// LDS frag arena: W0c chunks 0..15 @0, W1 chunks @16384. 53248 B total.
// Weights staged ONCE per block; grid-stride n-loop (~2 chunks/block) amortizes
// staging + uniform setup. 256 threads = 4 waves, 3 blocks/CU (LDS+regs).
__global__ __launch_bounds__(256, 3) void vdc_mlp_kernel(
    const float* __restrict__ feats,      // [N,32]
    const float* __restrict__ dirs,       // [C,N,3]
    const int* __restrict__ sh_deg_p,     // [1]
    const _Float16* __restrict__ ws,
    const float* __restrict__ b2p,        // [3]
    float* __restrict__ out,              // [C,N,3]
    int N, int C, int nchunk)
{
    __shared__ uint4 arena[3328];         // 53248 B
    char* lds = (char*)arena;

    const int tid   = threadIdx.x;
    const int c     = blockIdx.y;
    const int w     = tid >> 6;           // 0..3
    const int lane  = tid & 63;
    const int ln    = lane & 31;
    const int hl    = lane >> 5;

    const _Float16* w2p = ws + (size_t)C * 8192 + 18432;

    // ---- stage frag-linear weights into LDS (once per block) ----
    {
        const uint4* srcA = (const uint4*)(ws + (size_t)c * 8192);
        const uint4* srcB = (const uint4*)(ws + (size_t)C * 8192);
        #pragma unroll
        for (int it = 0; it < 13; ++it) {
            int idx = it * 256 + tid;
            arena[idx] = (idx < 1024) ? srcA[idx] : srcB[idx - 1024];
        }
    }

    // ---- uniform per-block setup (hoisted out of the n-loop) ----
    half8 bbias;
    {
        U4 ub;
        ub.u[0] = hl ? 0u : 0x00003C00u;   // f16 1.0 at k-offset 0, hl=0 only
        ub.u[1] = 0u; ub.u[2] = 0u; ub.u[3] = 0u;
        bbias = ub.h;
    }
    int deg = sh_deg_p[0];
    int nbu = (deg + 1) * (deg + 1);
    float b20 = b2p[0], b21 = b2p[1], b22 = b2p[2];

    // shared zero accumulator: opaque scalar so the compiler materializes the
    // 16-reg zero tile exactly once and every chain-start MFMA uses it as C
    // with a fresh D (no per-chain zero-init).
    float zf;
    asm volatile("v_mov_b32 %0, 0" : "=v"(zf));
    floatx16 z;
    #pragma unroll
    for (int r = 0; r < 16; ++r) z[r] = zf;

    __syncthreads();

    const char* fr = lds + lane * 16;     // per-lane frag base; chunk offsets imm

    for (int chunk = blockIdx.x; chunk < nchunk; chunk += gridDim.x) {
        const int base = chunk * 256 + w * 64;   // this wave's 64 elements
        int na = base + ln;      if (na >= N) na = N - 1;
        int nb = base + 32 + ln; if (nb >= N) nb = N - 1;

        half8 ax0, ax1, ax2, bx0, bx1, bx2;
        build_bfrags2(feats, dirs, (size_t)c * N, na, nb, hl, nbu,
                      ax0, ax1, ax2, bx0, bx1, bx2);

        // ---- layer 0 + transitions (named h-frags) ----
        half8 ha0, ha1, ha2, ha3, ha4, ha5, ha6, ha7;
        half8 hb0, hb1, hb2, hb3, hb4, hb5, hb6, hb7;
        half8 w2a0, w2b0, w2a1, w2b1, w2a2, w2b2, w2a3, w2b3;
        L0_MT(0, ha0, ha1, hb0, hb1);
        L0_MT(1, ha2, ha3, hb2, hb3);
        L0_MT(2, ha4, ha5, hb4, hb5);
        PFW2(0);                           // W2 pair for L1-MT0, covered by L0-MT3
        L0_MT(3, ha6, ha7, hb6, hb7);

        // ---- layer 1 with fused layer 2 (scalar o-accs, b2 folded in) ----
        float oa0 = b20, oa1 = b21, oa2 = b22;
        float ob0 = b20, ob1 = b21, ob2 = b22;
        L1_MT(0, w2a0, w2b0, PFW2(1));
        L1_MT(1, w2a1, w2b1, PFW2(2));
        L1_MT(2, w2a2, w2b2, PFW2(3));
        L1_MT(3, w2a3, w2b3, );

        // ct rows 0..2 at hl==0 are o=0,1,2 for col=ln
        if (hl == 0) {
            int nn = base + ln;
            if (nn < N) {
                float* op = out + ((size_t)c * N + nn) * 3;
                op[0] = oa0; op[1] = oa1; op[2] = oa2;
            }
            nn = base + 32 + ln;
            if (nn < N) {
                float* op = out + ((size_t)c * N + nn) * 3;
                op[0] = ob0; op[1] = ob1; op[2] = ob2;
            }
        }
    }
}

extern "C" void kernel_launch(void* const* d_in, const int* in_sizes, int n_in,
                              void* d_out, int out_size, void* d_ws, size_t ws_size,
                              hipStream_t stream) {
    const float* feats   = (const float*)d_in[0];
    const float* dirs    = (const float*)d_in[1];
    const float* emb_tab = (const float*)d_in[2];
    const float* W0      = (const float*)d_in[3];
    const float* b0      = (const float*)d_in[4];
    const float* W1      = (const float*)d_in[5];
    const float* b1      = (const float*)d_in[6];
    const float* W2      = (const float*)d_in[7];
    const float* b2      = (const float*)d_in[8];
    const int*   eids    = (const int*)d_in[9];
    const int*   shd     = (const int*)d_in[10];
    float* outp          = (float*)d_out;

    int N = in_sizes[0] / 32;    // features [N,32]
    int C = in_sizes[9];         // embed_ids [C]

    _Float16* wsh = (_Float16*)d_ws;

    int ws_elems = C * 8192 + 23040;
    vdc_prep_kernel<<<(ws_elems + 255) / 256, 256, 0, stream>>>(
        W0, W1, W2, b0, b1, b2, emb_tab, eids, C, wsh);

    int nchunk = (N + 255) / 256;
    int gx = (nchunk + 1) / 2;           // ~2 chunks per block
    if (gx < 1) gx = 1;
    dim3 grid(gx, C);
    vdc_mlp_kernel<<<grid, 256, 0, stream>>>(
        feats, dirs, shd, wsh, b2, outp, N, C, nchunk);
}

// Round 2
// 155.437 us; speedup vs baseline: 3.1737x; 3.1737x over previous
//
#include <hip/hip_runtime.h>
#include <cstdint>
#include <cstddef>

typedef _Float16 half8 __attribute__((ext_vector_type(8)));
typedef __fp16 fp16x2 __attribute__((ext_vector_type(2)));
typedef float floatx16 __attribute__((ext_vector_type(16)));
typedef unsigned uint2v __attribute__((ext_vector_type(2)));

// ws: frag-linear weight blobs. chunk = 1024 B = 64 lanes x 8 f16, lane l holds
// A[row = tile*32 + (l&31)][k = kchunk*16 + (l>>5)*8 + i], i=0..7.
//   W0c [C][16 chunks]  @ f16 0       (mt 0..3) x (ks 0..3); k<48: W0[(16+k)*128+j],
//                                     k==48: cbias(c,j)=b0[j]+emb_c.W0[0:16,j], else 0
//   W1  [36 chunks]     @ C*8192      (mt 0..3) x (ks 0..8); k<128: W1[k*128+j], k==128: b1[j], else 0
//   W2  [9 chunks]      @ C*8192+18432  (ks 0..8); o=(l&31): o<3 ? (k<128? W2[k*3+o] : k==128? b2[o] : 0) : 0

__global__ void vdc_prep_kernel(const float* __restrict__ W0,
                                const float* __restrict__ W1,
                                const float* __restrict__ W2,
                                const float* __restrict__ b0,
                                const float* __restrict__ b1,
                                const float* __restrict__ b2,
                                const float* __restrict__ emb_tab,
                                const int* __restrict__ embed_ids,
                                int C,
                                _Float16* __restrict__ ws) {
    int i = blockIdx.x * 256 + threadIdx.x;
    int w0end = C * 8192;
    int w1end = w0end + 18432;
    int w2end = w1end + 4608;
    float v = 0.0f;
    if (i < w0end) {
        int c = i >> 13, r = i & 8191;
        int ci = r >> 9, l = (r >> 3) & 63, ii = r & 7;
        int mt = ci >> 2, ks = ci & 3;
        int j  = mt * 32 + (l & 31);
        int kk = ks * 16 + (l >> 5) * 8 + ii;
        if (kk < 48) v = W0[(16 + kk) * 128 + j];
        else if (kk == 48) {
            int id = embed_ids[c];
            v = b0[j];
            #pragma unroll
            for (int e = 0; e < 16; ++e)
                v += emb_tab[(size_t)id * 16 + e] * W0[e * 128 + j];
        }
        ws[i] = (_Float16)v;
    } else if (i < w1end) {
        int r = i - w0end;
        int ci = r >> 9, l = (r >> 3) & 63, ii = r & 7;
        int mt = ci / 9, ks = ci - mt * 9;
        int j  = mt * 32 + (l & 31);
        int kk = ks * 16 + (l >> 5) * 8 + ii;
        if (kk < 128) v = W1[kk * 128 + j];
        else if (kk == 128) v = b1[j];
        ws[i] = (_Float16)v;
    } else if (i < w2end) {
        int r = i - w1end;
        int ks = r >> 9, l = (r >> 3) & 63, ii = r & 7;
        int o  = l & 31;
        int kk = ks * 16 + (l >> 5) * 8 + ii;
        if (o < 3) {
            if (kk < 128) v = W2[kk * 3 + o];
            else if (kk == 128) v = b2[o];
        }
        ws[i] = (_Float16)v;
    }
}

union U4 { unsigned u[4]; half8 h; };

__device__ __forceinline__ unsigned pkr(float a, float b) {
    union { fp16x2 h; unsigned u; } x;
    x.h = __builtin_amdgcn_cvt_pkrtz(a, b);
    return x.u;
}

// pack with round-toward-zero, then clamp both f16 halves to >= 0 (one v_pk_max_f16)
__device__ __forceinline__ unsigned pkrelu(float a, float b) {
    union { fp16x2 h; unsigned u; } x;
    x.h = __builtin_amdgcn_cvt_pkrtz(a, b);
    fp16x2 z = {(__fp16)0.0f, (__fp16)0.0f};
    x.h = __builtin_elementwise_max(x.h, z);
    return x.u;
}

// acc tile (C-layout) -> two B-frag half8 chunks (relu + pack + half-wave exchange).
// gfx950 v_permlane32_swap_b32: swap(x,y) -> {[x_lo,y_lo],[x_hi,y_hi]} — exactly
// the L/H recombination; replaces ds_bpermute+cndmask per pair.
__device__ __forceinline__ void transition(const floatx16& a, int hl,
                                           half8& lo, half8& hi) {
    unsigned p0 = pkrelu(a[0],  a[1]);
    unsigned p1 = pkrelu(a[2],  a[3]);
    unsigned p2 = pkrelu(a[4],  a[5]);
    unsigned p3 = pkrelu(a[6],  a[7]);
    unsigned p4 = pkrelu(a[8],  a[9]);
    unsigned p5 = pkrelu(a[10], a[11]);
    unsigned p6 = pkrelu(a[12], a[13]);
    unsigned p7 = pkrelu(a[14], a[15]);
    U4 L, H;
#if __has_builtin(__builtin_amdgcn_permlane32_swap)
    uint2v s02 = __builtin_amdgcn_permlane32_swap(p0, p2, false, false);
    uint2v s13 = __builtin_amdgcn_permlane32_swap(p1, p3, false, false);
    uint2v s46 = __builtin_amdgcn_permlane32_swap(p4, p6, false, false);
    uint2v s57 = __builtin_amdgcn_permlane32_swap(p5, p7, false, false);
    L.u[0] = s02[0]; L.u[1] = s13[0]; L.u[2] = s02[1]; L.u[3] = s13[1];
    H.u[0] = s46[0]; H.u[1] = s57[0]; H.u[2] = s46[1]; H.u[3] = s57[1];
    (void)hl;
#else
    unsigned r0 = __shfl_xor(hl ? p0 : p2, 32);
    unsigned r1 = __shfl_xor(hl ? p1 : p3, 32);
    unsigned r2 = __shfl_xor(hl ? p4 : p6, 32);
    unsigned r3 = __shfl_xor(hl ? p5 : p7, 32);
    L.u[0] = hl ? r0 : p0;
    L.u[1] = hl ? r1 : p1;
    L.u[2] = hl ? p2 : r0;
    L.u[3] = hl ? p3 : r1;
    H.u[0] = hl ? r2 : p4;
    H.u[1] = hl ? r3 : p5;
    H.u[2] = hl ? p6 : r2;
    H.u[3] = hl ? p7 : r3;
#endif
    lo = L.h; hi = H.h;
}

// SH frag (chunk 2) for one element given unnormalized dir
__device__ __forceinline__ void sh_frag(float dx, float dy, float dz,
                                        int hl, int nbu, half8& o2) {
    float nrm = sqrtf(dx * dx + dy * dy + dz * dz);
    float inv = 1.0f / fmaxf(nrm, 1e-12f);
    float x = dx * inv, y = dy * inv, z = dz * inv;

    float z2     = z * z;
    float fTmp0B = -1.092548430592079f * z;
    float fC1    = x * x - y * y;
    float fS1    = 2.0f * x * y;
    float fTmp0C = -2.285228997322329f * z2 + 0.4570457994644658f;
    float fTmp1B = 1.445305721320277f * z;
    float fC2    = x * fC1 - y * fS1;
    float fS2    = x * fS1 + y * fC1;

    float sh[16];
    sh[0]  = 0.2820947917738781f;
    sh[1]  = -0.48860251190292f * y;
    sh[2]  = 0.48860251190292f * z;
    sh[3]  = -0.48860251190292f * x;
    sh[4]  = 0.5462742152960395f * fS1;
    sh[5]  = fTmp0B * y;
    sh[6]  = 0.9461746957575601f * z2 - 0.3153915652525201f;
    sh[7]  = fTmp0B * x;
    sh[8]  = 0.5462742152960395f * fC1;
    sh[9]  = -0.5900435899266435f * fS2;
    sh[10] = fTmp1B * fS1;
    sh[11] = fTmp0C * y;
    sh[12] = z * (1.865881662950577f * z2 - 1.119528997770346f);
    sh[13] = fTmp0C * x;
    sh[14] = fTmp1B * fC1;
    sh[15] = -0.5900435899266435f * fC2;
    #pragma unroll
    for (int i = 0; i < 16; ++i) if (i >= nbu) sh[i] = 0.0f;

    float s0 = hl ? sh[8]  : sh[0];
    float s1 = hl ? sh[9]  : sh[1];
    float s2 = hl ? sh[10] : sh[2];
    float s3 = hl ? sh[11] : sh[3];
    float s4 = hl ? sh[12] : sh[4];
    float s5 = hl ? sh[13] : sh[5];
    float s6 = hl ? sh[14] : sh[6];
    float s7 = hl ? sh[15] : sh[7];
    U4 u2;
    u2.u[0] = pkr(s0, s1); u2.u[1] = pkr(s2, s3);
    u2.u[2] = pkr(s4, s5); u2.u[3] = pkr(s6, s7);
    o2 = u2.h;
}

// build layer0 B-frags for BOTH element tiles; all global loads issued before
// any math so the HBM latency is exposed once, not ~10 times.
__device__ __forceinline__ void build_bfrags2(
    const float* __restrict__ feats, const float* __restrict__ dirs,
    size_t cN, int na, int nb, int hl, int nbu,
    half8& ao0, half8& ao1, half8& ao2,
    half8& bo0, half8& bo1, half8& bo2)
{
    const float* fa = feats + (size_t)na * 32 + hl * 8;
    const float* fb = feats + (size_t)nb * 32 + hl * 8;
    float4 fa0 = *(const float4*)(fa);
    float4 fa1 = *(const float4*)(fa + 4);
    float4 fa2 = *(const float4*)(fa + 16);
    float4 fa3 = *(const float4*)(fa + 20);
    float4 fb0 = *(const float4*)(fb);
    float4 fb1 = *(const float4*)(fb + 4);
    float4 fb2 = *(const float4*)(fb + 16);
    float4 fb3 = *(const float4*)(fb + 20);
    const float* dpa = dirs + (cN + na) * 3;
    const float* dpb = dirs + (cN + nb) * 3;
    float dax = dpa[0], day = dpa[1], daz = dpa[2];
    float dbx = dpb[0], dby = dpb[1], dbz = dpb[2];

    U4 u;
    u.u[0] = pkr(fa0.x, fa0.y); u.u[1] = pkr(fa0.z, fa0.w);
    u.u[2] = pkr(fa1.x, fa1.y); u.u[3] = pkr(fa1.z, fa1.w);
    ao0 = u.h;
    u.u[0] = pkr(fa2.x, fa2.y); u.u[1] = pkr(fa2.z, fa2.w);
    u.u[2] = pkr(fa3.x, fa3.y); u.u[3] = pkr(fa3.z, fa3.w);
    ao1 = u.h;
    u.u[0] = pkr(fb0.x, fb0.y); u.u[1] = pkr(fb0.z, fb0.w);
    u.u[2] = pkr(fb1.x, fb1.y); u.u[3] = pkr(fb1.z, fb1.w);
    bo0 = u.h;
    u.u[0] = pkr(fb2.x, fb2.y); u.u[1] = pkr(fb2.z, fb2.w);
    u.u[2] = pkr(fb3.x, fb3.y); u.u[3] = pkr(fb3.z, fb3.w);
    bo1 = u.h;

    sh_frag(dax, day, daz, hl, nbu, ao2);
    sh_frag(dbx, dby, dbz, hl, nbu, bo2);
}

#define MFMA(a, b, c) __builtin_amdgcn_mfma_f32_32x32x16_f16((a), (b), (c), 0, 0, 0)
#define LDF(off) (*(const half8*)(fr + (off)))
#define GW2(ch) (*(const half8*)(w2p + (ch) * 512 + lane * 8))

// layer 0, tile MT: chains start from the shared opaque-zero C (D != C MFMA),
// killing the per-chain 16x v_accvgpr_write zero-init.
#define L0_MT(MT, HA0, HA1, HB0, HB1)                                    \
    do {                                                                 \
        half8 t0 = LDF(((MT) * 4 + 0) * 1024);                           \
        half8 t1 = LDF(((MT) * 4 + 1) * 1024);                           \
        half8 t2 = LDF(((MT) * 4 + 2) * 1024);                           \
        half8 t3 = LDF(((MT) * 4 + 3) * 1024);                           \
        floatx16 ca = MFMA(t0, ax0, z);                                  \
        floatx16 cb = MFMA(t0, bx0, z);                                  \
        ca = MFMA(t1, ax1, ca); cb = MFMA(t1, bx1, cb);                  \
        ca = MFMA(t2, ax2, ca); cb = MFMA(t2, bx2, cb);                  \
        ca = MFMA(t3, bbias, ca); cb = MFMA(t3, bbias, cb);              \
        transition(ca, hl, HA0, HA1);                                    \
        transition(cb, hl, HB0, HB1);                                    \
    } while (0)

#define L1_KS(MT, KS, HA, HB)                                            \
    do {                                                                 \
        half8 q = LDF(16384 + ((MT) * 9 + (KS)) * 1024);                 \
        ca = MFMA(q, HA, ca); cb = MFMA(q, HB, cb);                      \
    } while (0)

// layer 1 with fused layer-2: W2 pair loaded inside the tile (short live range,
// latency hidden under the remaining ~16 MFMAs of the chain); L2 accumulates
// into 3 scalar f32 per chain (no persistent acc3 AGPR tile).
#define L1_MT(MT)                                                        \
    do {                                                                 \
        floatx16 ca, cb;                                                 \
        { half8 q = LDF(16384 + ((MT) * 9 + 0) * 1024);                  \
          ca = MFMA(q, ha0, z); cb = MFMA(q, hb0, z); }                  \
        half8 w2a = GW2(2 * (MT) + 0);                                   \
        half8 w2b = GW2(2 * (MT) + 1);                                   \
        L1_KS(MT, 1, ha1, hb1);                                          \
        L1_KS(MT, 2, ha2, hb2);                                          \
        L1_KS(MT, 3, ha3, hb3);                                          \
        L1_KS(MT, 4, ha4, hb4);                                          \
        L1_KS(MT, 5, ha5, hb5);                                          \
        L1_KS(MT, 6, ha6, hb6);                                          \
        L1_KS(MT, 7, ha7, hb7);                                          \
        L1_KS(MT, 8, bbias, bbias);                                      \
        half8 g0, g1;                                                    \
        transition(ca, hl, g0, g1);                                      \
        { floatx16 ct = MFMA(w2a, g0, z); ct = MFMA(w2b, g1, ct);        \
          oa0 += ct[0]; oa1 += ct[1]; oa2 += ct[2]; }                    \
        transition(cb, hl, g0, g1);                                      \
        { floatx16 ct = MFMA(w2a, g0, z); ct = MFMA(w2b, g1, ct);        \
          ob0 += ct[0]; ob1 += ct[1]; ob2 += ct[2]; }                    \
    } while (0)

// LDS frag arena: W0c chunks 0..15 @0, W1 chunks @16384. 53248 B total.
// W2 frags read directly from global (9 KB, L1/L2-resident across all blocks).
// 256 threads = 4 waves, one 256-element chunk per block (round-1 lesson:
// grid-stride loop + W2 prefetch pipeline blew the register budget -> scratch).
__global__ __launch_bounds__(256, 3) void vdc_mlp_kernel(
    const float* __restrict__ feats,      // [N,32]
    const float* __restrict__ dirs,       // [C,N,3]
    const int* __restrict__ sh_deg_p,     // [1]
    const _Float16* __restrict__ ws,
    const float* __restrict__ b2p,        // [3]
    float* __restrict__ out,              // [C,N,3]
    int N, int C)
{
    __shared__ uint4 arena[3328];         // 53248 B
    char* lds = (char*)arena;

    const int tid   = threadIdx.x;
    const int c     = blockIdx.y;
    const int w     = tid >> 6;           // 0..3
    const int lane  = tid & 63;
    const int ln    = lane & 31;
    const int hl    = lane >> 5;
    const int base  = blockIdx.x * 256 + w * 64;   // this wave's 64 elements

    const _Float16* w2p = ws + (size_t)C * 8192 + 18432;

    // ---- stage frag-linear weights into LDS (coalesced, conflict-free) ----
    {
        const uint4* srcA = (const uint4*)(ws + (size_t)c * 8192);
        const uint4* srcB = (const uint4*)(ws + (size_t)C * 8192);
        #pragma unroll
        for (int it = 0; it < 13; ++it) {
            int idx = it * 256 + tid;
            arena[idx] = (idx < 1024) ? srcA[idx] : srcB[idx - 1024];
        }
    }

    // ---- build layer0 B-frags for both element tiles (overlaps staging) ----
    half8 bbias;
    {
        U4 ub;
        ub.u[0] = hl ? 0u : 0x00003C00u;   // f16 1.0 at k-offset 0, hl=0 only
        ub.u[1] = 0u; ub.u[2] = 0u; ub.u[3] = 0u;
        bbias = ub.h;
    }
    int deg = sh_deg_p[0];
    int nbu = (deg + 1) * (deg + 1);
    float b20 = b2p[0], b21 = b2p[1], b22 = b2p[2];

    int na = base + ln;      if (na >= N) na = N - 1;
    int nb = base + 32 + ln; if (nb >= N) nb = N - 1;
    half8 ax0, ax1, ax2, bx0, bx1, bx2;
    build_bfrags2(feats, dirs, (size_t)c * N, na, nb, hl, nbu,
                  ax0, ax1, ax2, bx0, bx1, bx2);

    // shared zero accumulator: opaque scalar so the compiler materializes the
    // 16-reg zero tile exactly once; every chain-start MFMA uses it as C with
    // a fresh D (no per-chain v_accvgpr_write zero-init).
    float zf;
    asm volatile("v_mov_b32 %0, 0" : "=v"(zf));
    floatx16 z;
    #pragma unroll
    for (int r = 0; r < 16; ++r) z[r] = zf;

    __syncthreads();

    const char* fr = lds + lane * 16;     // per-lane frag base; chunk offsets imm

    // ---- layer 0 + transitions (named h-frags) ----
    half8 ha0, ha1, ha2, ha3, ha4, ha5, ha6, ha7;
    half8 hb0, hb1, hb2, hb3, hb4, hb5, hb6, hb7;
    L0_MT(0, ha0, ha1, hb0, hb1);
    L0_MT(1, ha2, ha3, hb2, hb3);
    L0_MT(2, ha4, ha5, hb4, hb5);
    L0_MT(3, ha6, ha7, hb6, hb7);

    // ---- layer 1 with fused layer 2 (scalar o-accs, b2 folded in) ----
    float oa0 = b20, oa1 = b21, oa2 = b22;
    float ob0 = b20, ob1 = b21, ob2 = b22;
    L1_MT(0);
    L1_MT(1);
    L1_MT(2);
    L1_MT(3);

    // ct rows 0..2 at hl==0 are o=0,1,2 for col=ln
    if (hl == 0) {
        int nn = base + ln;
        if (nn < N) {
            float* op = out + ((size_t)c * N + nn) * 3;
            op[0] = oa0; op[1] = oa1; op[2] = oa2;
        }
        nn = base + 32 + ln;
        if (nn < N) {
            float* op = out + ((size_t)c * N + nn) * 3;
            op[0] = ob0; op[1] = ob1; op[2] = ob2;
        }
    }
}

extern "C" void kernel_launch(void* const* d_in, const int* in_sizes, int n_in,
                              void* d_out, int out_size, void* d_ws, size_t ws_size,
                              hipStream_t stream) {
    const float* feats   = (const float*)d_in[0];
    const float* dirs    = (const float*)d_in[1];
    const float* emb_tab = (const float*)d_in[2];
    const float* W0      = (const float*)d_in[3];
    const float* b0      = (const float*)d_in[4];
    const float* W1      = (const float*)d_in[5];
    const float* b1      = (const float*)d_in[6];
    const float* W2      = (const float*)d_in[7];
    const float* b2      = (const float*)d_in[8];
    const int*   eids    = (const int*)d_in[9];
    const int*   shd     = (const int*)d_in[10];
    float* outp          = (float*)d_out;

    int N = in_sizes[0] / 32;    // features [N,32]
    int C = in_sizes[9];         // embed_ids [C]

    _Float16* wsh = (_Float16*)d_ws;

    int ws_elems = C * 8192 + 23040;
    vdc_prep_kernel<<<(ws_elems + 255) / 256, 256, 0, stream>>>(
        W0, W1, W2, b0, b1, b2, emb_tab, eids, C, wsh);

    dim3 grid((N + 255) / 256, C);
    vdc_mlp_kernel<<<grid, 256, 0, stream>>>(
        feats, dirs, shd, wsh, b2, outp, N, C);
}

// Round 3
// 151.497 us; speedup vs baseline: 3.2563x; 1.0260x over previous
//
#include <hip/hip_runtime.h>
#include <cstdint>
#include <cstddef>

typedef _Float16 half8 __attribute__((ext_vector_type(8)));
typedef __fp16 fp16x2 __attribute__((ext_vector_type(2)));
typedef float floatx16 __attribute__((ext_vector_type(16)));
typedef unsigned uint2v __attribute__((ext_vector_type(2)));

// ws: frag-linear weight blobs. chunk = 1024 B = 64 lanes x 8 f16, lane l holds
// A[row = tile*32 + (l&31)][k = kchunk*16 + (l>>5)*8 + i], i=0..7.
//   W0c [C][16 chunks]  @ f16 0       (mt 0..3) x (ks 0..3); k<48: W0[(16+k)*128+j],
//                                     k==48: cbias(c,j)=b0[j]+emb_c.W0[0:16,j], else 0
//   W1  [36 chunks]     @ C*8192      (mt 0..3) x (ks 0..8); k<128: W1[k*128+j], k==128: b1[j], else 0
//   W2  [9 chunks]      @ C*8192+18432  (ks 0..8); o=(l&31): o<3 ? (k<128? W2[k*3+o] : k==128? b2[o] : 0) : 0

__global__ void vdc_prep_kernel(const float* __restrict__ W0,
                                const float* __restrict__ W1,
                                const float* __restrict__ W2,
                                const float* __restrict__ b0,
                                const float* __restrict__ b1,
                                const float* __restrict__ b2,
                                const float* __restrict__ emb_tab,
                                const int* __restrict__ embed_ids,
                                int C,
                                _Float16* __restrict__ ws) {
    int i = blockIdx.x * 256 + threadIdx.x;
    int w0end = C * 8192;
    int w1end = w0end + 18432;
    int w2end = w1end + 4608;
    float v = 0.0f;
    if (i < w0end) {
        int c = i >> 13, r = i & 8191;
        int ci = r >> 9, l = (r >> 3) & 63, ii = r & 7;
        int mt = ci >> 2, ks = ci & 3;
        int j  = mt * 32 + (l & 31);
        int kk = ks * 16 + (l >> 5) * 8 + ii;
        if (kk < 48) v = W0[(16 + kk) * 128 + j];
        else if (kk == 48) {
            int id = embed_ids[c];
            v = b0[j];
            #pragma unroll
            for (int e = 0; e < 16; ++e)
                v += emb_tab[(size_t)id * 16 + e] * W0[e * 128 + j];
        }
        ws[i] = (_Float16)v;
    } else if (i < w1end) {
        int r = i - w0end;
        int ci = r >> 9, l = (r >> 3) & 63, ii = r & 7;
        int mt = ci / 9, ks = ci - mt * 9;
        int j  = mt * 32 + (l & 31);
        int kk = ks * 16 + (l >> 5) * 8 + ii;
        if (kk < 128) v = W1[kk * 128 + j];
        else if (kk == 128) v = b1[j];
        ws[i] = (_Float16)v;
    } else if (i < w2end) {
        int r = i - w1end;
        int ks = r >> 9, l = (r >> 3) & 63, ii = r & 7;
        int o  = l & 31;
        int kk = ks * 16 + (l >> 5) * 8 + ii;
        if (o < 3) {
            if (kk < 128) v = W2[kk * 3 + o];
            else if (kk == 128) v = b2[o];
        }
        ws[i] = (_Float16)v;
    }
}

union U4 { unsigned u[4]; half8 h; };

__device__ __forceinline__ unsigned pkr(float a, float b) {
    union { fp16x2 h; unsigned u; } x;
    x.h = __builtin_amdgcn_cvt_pkrtz(a, b);
    return x.u;
}

// pack with round-toward-zero, then clamp both f16 halves to >= 0 (one v_pk_max_f16)
__device__ __forceinline__ unsigned pkrelu(float a, float b) {
    union { fp16x2 h; unsigned u; } x;
    x.h = __builtin_amdgcn_cvt_pkrtz(a, b);
    fp16x2 z = {(__fp16)0.0f, (__fp16)0.0f};
    x.h = __builtin_elementwise_max(x.h, z);
    return x.u;
}

__device__ __forceinline__ floatx16 zero16() {
    floatx16 z;
    #pragma unroll
    for (int r = 0; r < 16; ++r) z[r] = 0.0f;
    return z;
}

// acc tile (C-layout) -> two B-frag half8 chunks (relu + pack + half-wave exchange).
// gfx950 v_permlane32_swap_b32: swap(x,y) -> {[x_lo,y_lo],[x_hi,y_hi]} — exactly
// the L/H recombination; replaces ds_bpermute+cndmask per pair.
__device__ __forceinline__ void transition(const floatx16& a, int hl,
                                           half8& lo, half8& hi) {
    unsigned p0 = pkrelu(a[0],  a[1]);
    unsigned p1 = pkrelu(a[2],  a[3]);
    unsigned p2 = pkrelu(a[4],  a[5]);
    unsigned p3 = pkrelu(a[6],  a[7]);
    unsigned p4 = pkrelu(a[8],  a[9]);
    unsigned p5 = pkrelu(a[10], a[11]);
    unsigned p6 = pkrelu(a[12], a[13]);
    unsigned p7 = pkrelu(a[14], a[15]);
    U4 L, H;
#if __has_builtin(__builtin_amdgcn_permlane32_swap)
    uint2v s02 = __builtin_amdgcn_permlane32_swap(p0, p2, false, false);
    uint2v s13 = __builtin_amdgcn_permlane32_swap(p1, p3, false, false);
    uint2v s46 = __builtin_amdgcn_permlane32_swap(p4, p6, false, false);
    uint2v s57 = __builtin_amdgcn_permlane32_swap(p5, p7, false, false);
    L.u[0] = s02[0]; L.u[1] = s13[0]; L.u[2] = s02[1]; L.u[3] = s13[1];
    H.u[0] = s46[0]; H.u[1] = s57[0]; H.u[2] = s46[1]; H.u[3] = s57[1];
    (void)hl;
#else
    unsigned r0 = __shfl_xor(hl ? p0 : p2, 32);
    unsigned r1 = __shfl_xor(hl ? p1 : p3, 32);
    unsigned r2 = __shfl_xor(hl ? p4 : p6, 32);
    unsigned r3 = __shfl_xor(hl ? p5 : p7, 32);
    L.u[0] = hl ? r0 : p0;
    L.u[1] = hl ? r1 : p1;
    L.u[2] = hl ? p2 : r0;
    L.u[3] = hl ? p3 : r1;
    H.u[0] = hl ? r2 : p4;
    H.u[1] = hl ? r3 : p5;
    H.u[2] = hl ? p6 : r2;
    H.u[3] = hl ? p7 : r3;
#endif
    lo = L.h; hi = H.h;
}

// build layer0 B-frags (feats chunks 0,1 + SH chunk 2) for element n
__device__ __forceinline__ void build_bfrags(
    const float* __restrict__ feats, const float* __restrict__ dirs,
    size_t cN, int n, int hl, int nbu,
    half8& o0, half8& o1, half8& o2)
{
    const float* fp = feats + (size_t)n * 32 + hl * 8;
    float4 f0 = *(const float4*)(fp);
    float4 f1 = *(const float4*)(fp + 4);
    float4 f2 = *(const float4*)(fp + 16);
    float4 f3 = *(const float4*)(fp + 20);
    U4 u0, u1;
    u0.u[0] = pkr(f0.x, f0.y); u0.u[1] = pkr(f0.z, f0.w);
    u0.u[2] = pkr(f1.x, f1.y); u0.u[3] = pkr(f1.z, f1.w);
    u1.u[0] = pkr(f2.x, f2.y); u1.u[1] = pkr(f2.z, f2.w);
    u1.u[2] = pkr(f3.x, f3.y); u1.u[3] = pkr(f3.z, f3.w);
    o0 = u0.h; o1 = u1.h;

    const float* dp = dirs + (cN + n) * 3;
    float dx = dp[0], dy = dp[1], dz = dp[2];
    float nrm = sqrtf(dx * dx + dy * dy + dz * dz);
    float inv = 1.0f / fmaxf(nrm, 1e-12f);
    float x = dx * inv, y = dy * inv, z = dz * inv;

    float z2     = z * z;
    float fTmp0B = -1.092548430592079f * z;
    float fC1    = x * x - y * y;
    float fS1    = 2.0f * x * y;
    float fTmp0C = -2.285228997322329f * z2 + 0.4570457994644658f;
    float fTmp1B = 1.445305721320277f * z;
    float fC2    = x * fC1 - y * fS1;
    float fS2    = x * fS1 + y * fC1;

    float sh[16];
    sh[0]  = 0.2820947917738781f;
    sh[1]  = -0.48860251190292f * y;
    sh[2]  = 0.48860251190292f * z;
    sh[3]  = -0.48860251190292f * x;
    sh[4]  = 0.5462742152960395f * fS1;
    sh[5]  = fTmp0B * y;
    sh[6]  = 0.9461746957575601f * z2 - 0.3153915652525201f;
    sh[7]  = fTmp0B * x;
    sh[8]  = 0.5462742152960395f * fC1;
    sh[9]  = -0.5900435899266435f * fS2;
    sh[10] = fTmp1B * fS1;
    sh[11] = fTmp0C * y;
    sh[12] = z * (1.865881662950577f * z2 - 1.119528997770346f);
    sh[13] = fTmp0C * x;
    sh[14] = fTmp1B * fC1;
    sh[15] = -0.5900435899266435f * fC2;
    #pragma unroll
    for (int i = 0; i < 16; ++i) if (i >= nbu) sh[i] = 0.0f;

    float s0 = hl ? sh[8]  : sh[0];
    float s1 = hl ? sh[9]  : sh[1];
    float s2 = hl ? sh[10] : sh[2];
    float s3 = hl ? sh[11] : sh[3];
    float s4 = hl ? sh[12] : sh[4];
    float s5 = hl ? sh[13] : sh[5];
    float s6 = hl ? sh[14] : sh[6];
    float s7 = hl ? sh[15] : sh[7];
    U4 u2;
    u2.u[0] = pkr(s0, s1); u2.u[1] = pkr(s2, s3);
    u2.u[2] = pkr(s4, s5); u2.u[3] = pkr(s6, s7);
    o2 = u2.h;
}

#define MFMA(a, b, c) __builtin_amdgcn_mfma_f32_32x32x16_f16((a), (b), (c), 0, 0, 0)
#define LDF(off) (*(const half8*)(fr + (off)))
#define GW2(ch) (*(const half8*)(w2p + (ch) * 512 + lane * 8))

// layer 0, tile MT: each weight frag loaded once, consumed by both chains, dies.
// setprio(1) around the MFMA run only: with de-phased blocks, waves in their
// MFMA burst win issue arbitration over waves in their VALU (transition) burst.
#define L0_MT(MT, HA0, HA1, HB0, HB1)                                    \
    do {                                                                 \
        floatx16 ca = zero16();                                          \
        floatx16 cb = zero16();                                          \
        half8 t0 = LDF(((MT) * 4 + 0) * 1024);                           \
        __builtin_amdgcn_s_setprio(1);                                   \
        ca = MFMA(t0, ax0, ca); cb = MFMA(t0, bx0, cb);                  \
        half8 t1 = LDF(((MT) * 4 + 1) * 1024);                           \
        ca = MFMA(t1, ax1, ca); cb = MFMA(t1, bx1, cb);                  \
        half8 t2 = LDF(((MT) * 4 + 2) * 1024);                           \
        ca = MFMA(t2, ax2, ca); cb = MFMA(t2, bx2, cb);                  \
        half8 t3 = LDF(((MT) * 4 + 3) * 1024);                           \
        ca = MFMA(t3, bbias, ca); cb = MFMA(t3, bbias, cb);              \
        __builtin_amdgcn_s_setprio(0);                                   \
        transition(ca, hl, HA0, HA1);                                    \
        transition(cb, hl, HB0, HB1);                                    \
    } while (0)

#define L1_KS(MT, KS, HA, HB)                                            \
    do {                                                                 \
        half8 q = LDF(16384 + ((MT) * 9 + (KS)) * 1024);                 \
        ca = MFMA(q, HA, ca); cb = MFMA(q, HB, cb);                      \
    } while (0)

// layer 1 (+ fused layer 2) for one 32-row W1 tile MT, both element tiles
#define L1_MT(MT)                                                        \
    do {                                                                 \
        floatx16 ca = zero16();                                          \
        floatx16 cb = zero16();                                          \
        __builtin_amdgcn_s_setprio(1);                                   \
        L1_KS(MT, 0, ha0, hb0);                                          \
        L1_KS(MT, 1, ha1, hb1);                                          \
        L1_KS(MT, 2, ha2, hb2);                                          \
        L1_KS(MT, 3, ha3, hb3);                                          \
        L1_KS(MT, 4, ha4, hb4);                                          \
        L1_KS(MT, 5, ha5, hb5);                                          \
        L1_KS(MT, 6, ha6, hb6);                                          \
        L1_KS(MT, 7, ha7, hb7);                                          \
        L1_KS(MT, 8, bbias, bbias);                                      \
        __builtin_amdgcn_s_setprio(0);                                   \
        half8 w2a = GW2(2 * (MT) + 0);                                   \
        half8 w2b = GW2(2 * (MT) + 1);                                   \
        half8 g0, g1;                                                    \
        transition(ca, hl, g0, g1);                                      \
        acc3a = MFMA(w2a, g0, acc3a); acc3a = MFMA(w2b, g1, acc3a);      \
        transition(cb, hl, g0, g1);                                      \
        acc3b = MFMA(w2a, g0, acc3b); acc3b = MFMA(w2b, g1, acc3b);      \
    } while (0)

// LDS frag arena: W0c chunks 0..15 @0, W1 chunks @16384. 53248 B total.
// W2 frags read directly from global (9 KB, L1-resident across all blocks).
// 256 threads = 4 waves, EPW=2, load-use-die weight frags, (256,3) -> no spill,
// 3 blocks/CU x 4 waves = 12 waves/CU (LDS: 3*53248 <= 160K).
// Round-1/2 lesson: ANY persistent-register addition (z tile, prefetch pipe,
// n-loop) spills -> scratch storms. This is the verified-60us round-0 body
// plus two zero-register changes: per-block s_sleep de-phasing + setprio.
__global__ __launch_bounds__(256, 3) void vdc_mlp_kernel(
    const float* __restrict__ feats,      // [N,32]
    const float* __restrict__ dirs,       // [C,N,3]
    const int* __restrict__ sh_deg_p,     // [1]
    const _Float16* __restrict__ ws,
    float* __restrict__ out,              // [C,N,3]
    int N, int C)
{
    __shared__ uint4 arena[3328];         // 53248 B
    char* lds = (char*)arena;

    const int tid   = threadIdx.x;
    const int c     = blockIdx.y;
    const int w     = tid >> 6;           // 0..3
    const int lane  = tid & 63;
    const int ln    = lane & 31;
    const int hl    = lane >> 5;
    const int base  = blockIdx.x * 256 + w * 64;   // this wave's 64 elements

    const _Float16* w2p = ws + (size_t)C * 8192 + 18432;

    // ---- stage frag-linear weights into LDS (coalesced, conflict-free) ----
    {
        const uint4* srcA = (const uint4*)(ws + (size_t)c * 8192);
        const uint4* srcB = (const uint4*)(ws + (size_t)C * 8192);
        #pragma unroll
        for (int it = 0; it < 13; ++it) {
            int idx = it * 256 + tid;
            arena[idx] = (idx < 1024) ? srcA[idx] : srcB[idx - 1024];
        }
    }

    // ---- build layer0 B-frags for both element tiles (overlaps staging) ----
    half8 bbias;
    {
        U4 ub;
        ub.u[0] = hl ? 0u : 0x00003C00u;   // f16 1.0 at k-offset 0, hl=0 only
        ub.u[1] = 0u; ub.u[2] = 0u; ub.u[3] = 0u;
        bbias = ub.h;
    }
    int deg = sh_deg_p[0];
    int nbu = (deg + 1) * (deg + 1);
    int na = base + ln;      if (na >= N) na = N - 1;
    int nb = base + 32 + ln; if (nb >= N) nb = N - 1;
    half8 ax0, ax1, ax2, bx0, bx1, bx2;
    build_bfrags(feats, dirs, (size_t)c * N, na, hl, nbu, ax0, ax1, ax2);
    build_bfrags(feats, dirs, (size_t)c * N, nb, hl, nbu, bx0, bx1, bx2);

    __syncthreads();

    // ---- de-phase co-resident blocks (identical code runs in lockstep ->
    // all waves on a SIMD hit VALU/MFMA bursts together; offset by ~1/3 and
    // ~2/3 of an MT period so bursts interleave across blocks). Co-resident
    // blocks differ in dispatch round -> distinct (linear_id >> 8) mod 3.
    {
        int rphase = ((blockIdx.x >> 8) + blockIdx.y) % 3;
        for (int i = 0; i < rphase; ++i) __builtin_amdgcn_s_sleep(3);
    }

    const char* fr = lds + lane * 16;     // per-lane frag base; chunk offsets imm

    // ---- layer 0 + transitions (named h-frags) ----
    half8 ha0, ha1, ha2, ha3, ha4, ha5, ha6, ha7;
    half8 hb0, hb1, hb2, hb3, hb4, hb5, hb6, hb7;
    L0_MT(0, ha0, ha1, hb0, hb1);
    L0_MT(1, ha2, ha3, hb2, hb3);
    L0_MT(2, ha4, ha5, hb4, hb5);
    L0_MT(3, ha6, ha7, hb6, hb7);

    // ---- layer 1 with fused layer 2 ----
    floatx16 acc3a = zero16();
    floatx16 acc3b = zero16();
    L1_MT(0);
    L1_MT(1);
    L1_MT(2);
    L1_MT(3);
    {
        half8 ab = GW2(8);
        acc3a = MFMA(ab, bbias, acc3a);
        acc3b = MFMA(ab, bbias, acc3b);
    }

    // D: col = e = ln, row = (r&3)+8*(r>>2)+4*hl -> hl=0 regs 0,1,2 are o=0,1,2
    if (hl == 0) {
        int nn = base + ln;
        if (nn < N) {
            float* op = out + ((size_t)c * N + nn) * 3;
            op[0] = acc3a[0];
            op[1] = acc3a[1];
            op[2] = acc3a[2];
        }
        nn = base + 32 + ln;
        if (nn < N) {
            float* op = out + ((size_t)c * N + nn) * 3;
            op[0] = acc3b[0];
            op[1] = acc3b[1];
            op[2] = acc3b[2];
        }
    }
}

extern "C" void kernel_launch(void* const* d_in, const int* in_sizes, int n_in,
                              void* d_out, int out_size, void* d_ws, size_t ws_size,
                              hipStream_t stream) {
    const float* feats   = (const float*)d_in[0];
    const float* dirs    = (const float*)d_in[1];
    const float* emb_tab = (const float*)d_in[2];
    const float* W0      = (const float*)d_in[3];
    const float* b0      = (const float*)d_in[4];
    const float* W1      = (const float*)d_in[5];
    const float* b1      = (const float*)d_in[6];
    const float* W2      = (const float*)d_in[7];
    const float* b2      = (const float*)d_in[8];
    const int*   eids    = (const int*)d_in[9];
    const int*   shd     = (const int*)d_in[10];
    float* outp          = (float*)d_out;

    int N = in_sizes[0] / 32;    // features [N,32]
    int C = in_sizes[9];         // embed_ids [C]

    _Float16* wsh = (_Float16*)d_ws;

    int ws_elems = C * 8192 + 23040;
    vdc_prep_kernel<<<(ws_elems + 255) / 256, 256, 0, stream>>>(
        W0, W1, W2, b0, b1, b2, emb_tab, eids, C, wsh);

    dim3 grid((N + 255) / 256, C);
    vdc_mlp_kernel<<<grid, 256, 0, stream>>>(
        feats, dirs, shd, wsh, outp, N, C);
}

// Round 4
// 148.065 us; speedup vs baseline: 3.3318x; 1.0232x over previous
//
#include <hip/hip_runtime.h>
#include <cstdint>
#include <cstddef>

typedef _Float16 half8 __attribute__((ext_vector_type(8)));
typedef __fp16 fp16x2 __attribute__((ext_vector_type(2)));
typedef float floatx16 __attribute__((ext_vector_type(16)));
typedef unsigned uint2v __attribute__((ext_vector_type(2)));

// ws: frag-linear weight blobs. chunk = 1024 B = 64 lanes x 8 f16, lane l holds
// A[row = tile*32 + (l&31)][k = kchunk*16 + (l>>5)*8 + i], i=0..7.
//   W0c [C][12 chunks] @ f16 0          (mt 0..3) x (ks 0..2); kk 0..47: W0[(16+kk)*128+j]
//   W1  [32 chunks]    @ C*6144         (mt 0..3) x (ks 0..7); kk 0..127: W1[kk*128+j]
//   W2  [8 chunks]     @ C*6144+16384   (ks 0..7); o=(l&31): o<3 ? W2[kk*3+o] : 0
//   f32 tail @ f16 C*6144+20480: cbias[C][128] (b0 + emb_c @ W0[0:16,:]), b1[128]
// Biases are NOT MFMA'd anymore: cbias/b1 become the C-operand init of each
// accumulation chain (4x broadcast ds_read_b128); b2 is added at the store.

__global__ void vdc_prep_kernel(const float* __restrict__ W0,
                                const float* __restrict__ W1,
                                const float* __restrict__ W2,
                                const float* __restrict__ b0,
                                const float* __restrict__ b1,
                                const float* __restrict__ emb_tab,
                                const int* __restrict__ embed_ids,
                                int C,
                                _Float16* __restrict__ ws) {
    int i = blockIdx.x * 256 + threadIdx.x;
    int w0end   = C * 6144;
    int w1end   = w0end + 16384;
    int w2end   = w1end + 4096;
    int tailend = w2end + C * 128 + 128;
    if (i < w0end) {
        int c = i / 6144, r = i - c * 6144;
        int ci = r >> 9, l = (r >> 3) & 63, ii = r & 7;
        int mt = ci / 3, ks = ci - mt * 3;        // ci 0..11
        int j  = mt * 32 + (l & 31);
        int kk = ks * 16 + (l >> 5) * 8 + ii;     // 0..47
        ws[i] = (_Float16)W0[(16 + kk) * 128 + j];
    } else if (i < w1end) {
        int r = i - w0end;
        int ci = r >> 9, l = (r >> 3) & 63, ii = r & 7;
        int mt = ci >> 3, ks = ci & 7;            // ci 0..31
        int j  = mt * 32 + (l & 31);
        int kk = ks * 16 + (l >> 5) * 8 + ii;     // 0..127
        ws[i] = (_Float16)W1[kk * 128 + j];
    } else if (i < w2end) {
        int r = i - w1end;
        int ks = r >> 9, l = (r >> 3) & 63, ii = r & 7;
        int o  = l & 31;
        int kk = ks * 16 + (l >> 5) * 8 + ii;     // 0..127
        float v = 0.0f;
        if (o < 3) v = W2[kk * 3 + o];
        ws[i] = (_Float16)v;
    } else if (i < tailend) {
        int t = i - w2end;
        float* tail = (float*)(ws + w2end);       // byte off (C*6144+20480)*2, 16-aligned
        float v;
        if (t < C * 128) {
            int c = t >> 7, j = t & 127;
            int id = embed_ids[c];
            v = b0[j];
            #pragma unroll
            for (int e = 0; e < 16; ++e)
                v += emb_tab[(size_t)id * 16 + e] * W0[e * 128 + j];
        } else {
            v = b1[t - C * 128];
        }
        tail[t] = v;
    }
}

union U4 { unsigned u[4]; half8 h; };

__device__ __forceinline__ unsigned pkr(float a, float b) {
    union { fp16x2 h; unsigned u; } x;
    x.h = __builtin_amdgcn_cvt_pkrtz(a, b);
    return x.u;
}

// pack with round-toward-zero, then clamp both f16 halves to >= 0 (one v_pk_max_f16)
__device__ __forceinline__ unsigned pkrelu(float a, float b) {
    union { fp16x2 h; unsigned u; } x;
    x.h = __builtin_amdgcn_cvt_pkrtz(a, b);
    fp16x2 z = {(__fp16)0.0f, (__fp16)0.0f};
    x.h = __builtin_elementwise_max(x.h, z);
    return x.u;
}

__device__ __forceinline__ floatx16 zero16() {
    floatx16 z;
    #pragma unroll
    for (int r = 0; r < 16; ++r) z[r] = 0.0f;
    return z;
}

// acc tile (C-layout) -> two B-frag half8 chunks (relu + pack + half-wave exchange).
// gfx950 v_permlane32_swap_b32: swap(x,y) -> {[x_lo,y_lo],[x_hi,y_hi]} — exactly
// the L/H recombination; replaces ds_bpermute+cndmask per pair.
__device__ __forceinline__ void transition(const floatx16& a, int hl,
                                           half8& lo, half8& hi) {
    unsigned p0 = pkrelu(a[0],  a[1]);
    unsigned p1 = pkrelu(a[2],  a[3]);
    unsigned p2 = pkrelu(a[4],  a[5]);
    unsigned p3 = pkrelu(a[6],  a[7]);
    unsigned p4 = pkrelu(a[8],  a[9]);
    unsigned p5 = pkrelu(a[10], a[11]);
    unsigned p6 = pkrelu(a[12], a[13]);
    unsigned p7 = pkrelu(a[14], a[15]);
    U4 L, H;
#if __has_builtin(__builtin_amdgcn_permlane32_swap)
    uint2v s02 = __builtin_amdgcn_permlane32_swap(p0, p2, false, false);
    uint2v s13 = __builtin_amdgcn_permlane32_swap(p1, p3, false, false);
    uint2v s46 = __builtin_amdgcn_permlane32_swap(p4, p6, false, false);
    uint2v s57 = __builtin_amdgcn_permlane32_swap(p5, p7, false, false);
    L.u[0] = s02[0]; L.u[1] = s13[0]; L.u[2] = s02[1]; L.u[3] = s13[1];
    H.u[0] = s46[0]; H.u[1] = s57[0]; H.u[2] = s46[1]; H.u[3] = s57[1];
    (void)hl;
#else
    unsigned r0 = __shfl_xor(hl ? p0 : p2, 32);
    unsigned r1 = __shfl_xor(hl ? p1 : p3, 32);
    unsigned r2 = __shfl_xor(hl ? p4 : p6, 32);
    unsigned r3 = __shfl_xor(hl ? p5 : p7, 32);
    L.u[0] = hl ? r0 : p0;
    L.u[1] = hl ? r1 : p1;
    L.u[2] = hl ? p2 : r0;
    L.u[3] = hl ? p3 : r1;
    H.u[0] = hl ? r2 : p4;
    H.u[1] = hl ? r3 : p5;
    H.u[2] = hl ? p6 : r2;
    H.u[3] = hl ? p7 : r3;
#endif
    lo = L.h; hi = H.h;
}

// build layer0 B-frags (feats chunks 0,1 + SH chunk 2) for element n
__device__ __forceinline__ void build_bfrags(
    const float* __restrict__ feats, const float* __restrict__ dirs,
    size_t cN, int n, int hl, int nbu,
    half8& o0, half8& o1, half8& o2)
{
    const float* fp = feats + (size_t)n * 32 + hl * 8;
    float4 f0 = *(const float4*)(fp);
    float4 f1 = *(const float4*)(fp + 4);
    float4 f2 = *(const float4*)(fp + 16);
    float4 f3 = *(const float4*)(fp + 20);
    U4 u0, u1;
    u0.u[0] = pkr(f0.x, f0.y); u0.u[1] = pkr(f0.z, f0.w);
    u0.u[2] = pkr(f1.x, f1.y); u0.u[3] = pkr(f1.z, f1.w);
    u1.u[0] = pkr(f2.x, f2.y); u1.u[1] = pkr(f2.z, f2.w);
    u1.u[2] = pkr(f3.x, f3.y); u1.u[3] = pkr(f3.z, f3.w);
    o0 = u0.h; o1 = u1.h;

    const float* dp = dirs + (cN + n) * 3;
    float dx = dp[0], dy = dp[1], dz = dp[2];
    float nrm = sqrtf(dx * dx + dy * dy + dz * dz);
    float inv = 1.0f / fmaxf(nrm, 1e-12f);
    float x = dx * inv, y = dy * inv, z = dz * inv;

    float z2     = z * z;
    float fTmp0B = -1.092548430592079f * z;
    float fC1    = x * x - y * y;
    float fS1    = 2.0f * x * y;
    float fTmp0C = -2.285228997322329f * z2 + 0.4570457994644658f;
    float fTmp1B = 1.445305721320277f * z;
    float fC2    = x * fC1 - y * fS1;
    float fS2    = x * fS1 + y * fC1;

    float sh[16];
    sh[0]  = 0.2820947917738781f;
    sh[1]  = -0.48860251190292f * y;
    sh[2]  = 0.48860251190292f * z;
    sh[3]  = -0.48860251190292f * x;
    sh[4]  = 0.5462742152960395f * fS1;
    sh[5]  = fTmp0B * y;
    sh[6]  = 0.9461746957575601f * z2 - 0.3153915652525201f;
    sh[7]  = fTmp0B * x;
    sh[8]  = 0.5462742152960395f * fC1;
    sh[9]  = -0.5900435899266435f * fS2;
    sh[10] = fTmp1B * fS1;
    sh[11] = fTmp0C * y;
    sh[12] = z * (1.865881662950577f * z2 - 1.119528997770346f);
    sh[13] = fTmp0C * x;
    sh[14] = fTmp1B * fC1;
    sh[15] = -0.5900435899266435f * fC2;
    #pragma unroll
    for (int i = 0; i < 16; ++i) if (i >= nbu) sh[i] = 0.0f;

    float s0 = hl ? sh[8]  : sh[0];
    float s1 = hl ? sh[9]  : sh[1];
    float s2 = hl ? sh[10] : sh[2];
    float s3 = hl ? sh[11] : sh[3];
    float s4 = hl ? sh[12] : sh[4];
    float s5 = hl ? sh[13] : sh[5];
    float s6 = hl ? sh[14] : sh[6];
    float s7 = hl ? sh[15] : sh[7];
    U4 u2;
    u2.u[0] = pkr(s0, s1); u2.u[1] = pkr(s2, s3);
    u2.u[2] = pkr(s4, s5); u2.u[3] = pkr(s6, s7);
    o2 = u2.h;
}

#define MFMA(a, b, c) __builtin_amdgcn_mfma_f32_32x32x16_f16((a), (b), (c), 0, 0, 0)
#define LDF(off) (*(const half8*)(fr + (off)))
#define GW2(ch) (*(const half8*)(w2p + (ch) * 512 + lane * 8))

// bias -> accumulator-C init. C/D row mapping: j = MT*32 + (r&3)+8*(r>>2)+4*hl,
// col = ln. Rows for reg-quad q are 4 contiguous f32 at j = MT*32 + 8q + 4hl
// -> 4x broadcast ds_read_b128 (same addr across each half-wave: conflict-free).
#define INIT_CB(DST, TAILOFF, MT)                                        \
    do {                                                                 \
        const float4* bp_ = (const float4*)(lds + (TAILOFF)) + (MT) * 8 + hl; \
        union { float4 f4[4]; floatx16 x; } ci_;                         \
        ci_.f4[0] = bp_[0]; ci_.f4[1] = bp_[2];                          \
        ci_.f4[2] = bp_[4]; ci_.f4[3] = bp_[6];                          \
        DST = ci_.x;                                                     \
    } while (0)

// layer 0, tile MT: chains start from cbias (no zero-init, no bias MFMA);
// each weight frag loaded once, consumed by both chains, dies.
#define L0_MT(MT, HA0, HA1, HB0, HB1)                                    \
    do {                                                                 \
        floatx16 ca, cb;                                                 \
        INIT_CB(ca, 45056, MT);                                          \
        INIT_CB(cb, 45056, MT);                                          \
        half8 t0 = LDF(((MT) * 3 + 0) * 1024);                           \
        ca = MFMA(t0, ax0, ca); cb = MFMA(t0, bx0, cb);                  \
        half8 t1 = LDF(((MT) * 3 + 1) * 1024);                           \
        ca = MFMA(t1, ax1, ca); cb = MFMA(t1, bx1, cb);                  \
        half8 t2 = LDF(((MT) * 3 + 2) * 1024);                           \
        ca = MFMA(t2, ax2, ca); cb = MFMA(t2, bx2, cb);                  \
        transition(ca, hl, HA0, HA1);                                    \
        transition(cb, hl, HB0, HB1);                                    \
    } while (0)

#define L1_KS(MT, KS, HA, HB)                                            \
    do {                                                                 \
        half8 q = LDF(12288 + ((MT) * 8 + (KS)) * 1024);                 \
        ca = MFMA(q, HA, ca); cb = MFMA(q, HB, cb);                      \
    } while (0)

// layer 1 (+ fused layer 2) for one 32-row W1 tile MT, both element tiles;
// chains start from b1 (no zero-init, no bias MFMA).
#define L1_MT(MT)                                                        \
    do {                                                                 \
        floatx16 ca, cb;                                                 \
        INIT_CB(ca, 45568, MT);                                          \
        INIT_CB(cb, 45568, MT);                                          \
        L1_KS(MT, 0, ha0, hb0);                                          \
        L1_KS(MT, 1, ha1, hb1);                                          \
        L1_KS(MT, 2, ha2, hb2);                                          \
        L1_KS(MT, 3, ha3, hb3);                                          \
        L1_KS(MT, 4, ha4, hb4);                                          \
        L1_KS(MT, 5, ha5, hb5);                                          \
        L1_KS(MT, 6, ha6, hb6);                                          \
        L1_KS(MT, 7, ha7, hb7);                                          \
        half8 w2a = GW2(2 * (MT) + 0);                                   \
        half8 w2b = GW2(2 * (MT) + 1);                                   \
        half8 g0, g1;                                                    \
        transition(ca, hl, g0, g1);                                      \
        acc3a = MFMA(w2a, g0, acc3a); acc3a = MFMA(w2b, g1, acc3a);      \
        transition(cb, hl, g0, g1);                                      \
        acc3b = MFMA(w2a, g0, acc3b); acc3b = MFMA(w2b, g1, acc3b);      \
    } while (0)

// LDS arena: W0c 12 chunks @0, W1 32 chunks @12288, cbias_c f32 @45056,
// b1 f32 @45568. 46080 B total. W2 frags read from global (L1/L2-resident).
// 256 threads = 4 waves, load-use-die weight frags, (256,3) -> no spill,
// 3 blocks/CU x 4 waves = 12 waves/CU. Round-1/2 lesson: no persistent-register
// additions (z tile / prefetch pipe / n-loop all spilled). Round-3 lesson:
// s_sleep de-phasing + setprio are null-to-negative -> removed.
__global__ __launch_bounds__(256, 3) void vdc_mlp_kernel(
    const float* __restrict__ feats,      // [N,32]
    const float* __restrict__ dirs,       // [C,N,3]
    const int* __restrict__ sh_deg_p,     // [1]
    const _Float16* __restrict__ ws,
    const float* __restrict__ b2p,        // [3]
    float* __restrict__ out,              // [C,N,3]
    int N, int C)
{
    __shared__ uint4 arena[2880];         // 46080 B
    char* lds = (char*)arena;

    const int tid   = threadIdx.x;
    const int c     = blockIdx.y;
    const int w     = tid >> 6;           // 0..3
    const int lane  = tid & 63;
    const int ln    = lane & 31;
    const int hl    = lane >> 5;
    const int base  = blockIdx.x * 256 + w * 64;   // this wave's 64 elements

    const _Float16* w2p = ws + (size_t)C * 6144 + 16384;

    // ---- stage frag-linear weights + f32 biases into LDS ----
    {
        const uint4* srcA = (const uint4*)(ws + (size_t)c * 6144);        // 768: W0c
        const uint4* srcB = (const uint4*)(ws + (size_t)C * 6144);        // 2048: W1
        const float* tail = (const float*)(ws + (size_t)C * 6144 + 20480);
        const uint4* srcC = (const uint4*)(tail + (size_t)c * 128);       // 32: cbias_c
        const uint4* srcD = (const uint4*)(tail + (size_t)C * 128);       // 32: b1
        #pragma unroll
        for (int it = 0; it < 12; ++it) {
            int idx = it * 256 + tid;
            if (idx < 2880) {
                const uint4* p;
                if (idx < 768)       p = srcA + idx;
                else if (idx < 2816) p = srcB + (idx - 768);
                else if (idx < 2848) p = srcC + (idx - 2816);
                else                 p = srcD + (idx - 2848);
                arena[idx] = *p;
            }
        }
    }

    // ---- build layer0 B-frags for both element tiles (overlaps staging) ----
    int deg = sh_deg_p[0];
    int nbu = (deg + 1) * (deg + 1);
    float b20 = b2p[0], b21 = b2p[1], b22 = b2p[2];   // uniform -> SGPRs
    int na = base + ln;      if (na >= N) na = N - 1;
    int nb = base + 32 + ln; if (nb >= N) nb = N - 1;
    half8 ax0, ax1, ax2, bx0, bx1, bx2;
    build_bfrags(feats, dirs, (size_t)c * N, na, hl, nbu, ax0, ax1, ax2);
    build_bfrags(feats, dirs, (size_t)c * N, nb, hl, nbu, bx0, bx1, bx2);

    __syncthreads();

    const char* fr = lds + lane * 16;     // per-lane frag base; chunk offsets imm

    // ---- layer 0 + transitions (named h-frags) ----
    half8 ha0, ha1, ha2, ha3, ha4, ha5, ha6, ha7;
    half8 hb0, hb1, hb2, hb3, hb4, hb5, hb6, hb7;
    L0_MT(0, ha0, ha1, hb0, hb1);
    L0_MT(1, ha2, ha3, hb2, hb3);
    L0_MT(2, ha4, ha5, hb4, hb5);
    L0_MT(3, ha6, ha7, hb6, hb7);

    // ---- layer 1 with fused layer 2 ----
    floatx16 acc3a = zero16();
    floatx16 acc3b = zero16();
    L1_MT(0);
    L1_MT(1);
    L1_MT(2);
    L1_MT(3);

    // D: col = e = ln, row = (r&3)+8*(r>>2)+4*hl -> hl=0 regs 0,1,2 are o=0,1,2
    if (hl == 0) {
        int nn = base + ln;
        if (nn < N) {
            float* op = out + ((size_t)c * N + nn) * 3;
            op[0] = acc3a[0] + b20;
            op[1] = acc3a[1] + b21;
            op[2] = acc3a[2] + b22;
        }
        nn = base + 32 + ln;
        if (nn < N) {
            float* op = out + ((size_t)c * N + nn) * 3;
            op[0] = acc3b[0] + b20;
            op[1] = acc3b[1] + b21;
            op[2] = acc3b[2] + b22;
        }
    }
}

extern "C" void kernel_launch(void* const* d_in, const int* in_sizes, int n_in,
                              void* d_out, int out_size, void* d_ws, size_t ws_size,
                              hipStream_t stream) {
    const float* feats   = (const float*)d_in[0];
    const float* dirs    = (const float*)d_in[1];
    const float* emb_tab = (const float*)d_in[2];
    const float* W0      = (const float*)d_in[3];
    const float* b0      = (const float*)d_in[4];
    const float* W1      = (const float*)d_in[5];
    const float* b1      = (const float*)d_in[6];
    const float* W2      = (const float*)d_in[7];
    const float* b2      = (const float*)d_in[8];
    const int*   eids    = (const int*)d_in[9];
    const int*   shd     = (const int*)d_in[10];
    float* outp          = (float*)d_out;

    int N = in_sizes[0] / 32;    // features [N,32]
    int C = in_sizes[9];         // embed_ids [C]

    _Float16* wsh = (_Float16*)d_ws;

    int ws_threads = C * 6144 + 20480 + C * 128 + 128;
    vdc_prep_kernel<<<(ws_threads + 255) / 256, 256, 0, stream>>>(
        W0, W1, W2, b0, b1, emb_tab, eids, C, wsh);

    dim3 grid((N + 255) / 256, C);
    vdc_mlp_kernel<<<grid, 256, 0, stream>>>(
        feats, dirs, shd, wsh, b2, outp, N, C);
}